// Round 1
// baseline (1224.143 us; speedup 1.0000x reference)
//
#include <hip/hip_runtime.h>
#include <hip/hip_bf16.h>

// Problem: NGCFModel — U=256, I=1024, B=512, E=64
// out = (xui[512], gamma_u[512,64], gamma_i_i[512,64]) concatenated fp32.
//
// Math: rs[u,i] = sum_d cnt_d * T[u, item_d, i]   (d over distinct items)
//       v[u,:]  = normalize( sum_j rs[u, items[j]] * gi[j,:] )
//       out: xui[b] = dot(gu[b], v[users[b]]), gamma_u = gu, gamma_i_i[b] = v[users[b]]
//
// Traffic floor: ~221 users x ~403 items x 4KB = ~360 MB of T -> ~57 us @ 6.3 TB/s.

#define U_CNT 256
#define I_CNT 1024
#define B_CNT 512
#define E_CNT 64
#define CMAX  528   // max distinct items (<=512) padded to mult of 16 + slack

// ---------------- Kernel A: histogram items, compact items & users ----------
__global__ __launch_bounds__(1024) void setup_kernel(
    const int* __restrict__ users, const int* __restrict__ items,
    int* __restrict__ citems, float* __restrict__ ccnts,
    int* __restrict__ cusers, int* __restrict__ meta) {
  __shared__ int cnt[I_CNT];
  __shared__ int ucnt[U_CNT];
  __shared__ int dcount, ucount;
  int tid = threadIdx.x;
  cnt[tid] = 0;
  if (tid < U_CNT) ucnt[tid] = 0;
  if (tid == 0) { dcount = 0; ucount = 0; }
  __syncthreads();
  if (tid < B_CNT) {
    atomicAdd(&cnt[items[tid]], 1);
    atomicAdd(&ucnt[users[tid]], 1);
  }
  __syncthreads();
  int c = cnt[tid];
  if (c > 0) {
    int pos = atomicAdd(&dcount, 1);
    citems[pos] = tid;
    ccnts[pos]  = (float)c;
  }
  if (tid < U_CNT && ucnt[tid] > 0) {
    int pos = atomicAdd(&ucount, 1);
    cusers[pos] = tid;
  }
  __syncthreads();
  int D = dcount;
  int Dpad = (D + 15) & ~15;   // multiple of 16 so each half is a multiple of 8
  if (tid >= D && tid < Dpad) { citems[tid] = 0; ccnts[tid] = 0.0f; }
  if (tid == 0) { meta[0] = Dpad; meta[1] = ucount; }
}

// ---------------- Kernel B: partial rowsums, float4, compacted users --------
// grid = 2*U blocks (worker, item-half), 256 threads. Each block covers the
// FULL 1024-col row (256 x float4) for half the distinct items, writing a
// partial plane rs2[half][u][1024]. No atomics; planes summed in kernel C.
__global__ __launch_bounds__(256) void rowsum_kernel(
    const float* __restrict__ T, const int* __restrict__ citems,
    const float* __restrict__ ccnts, const int* __restrict__ cusers,
    const int* __restrict__ meta, float* __restrict__ rs2) {
  int w    = blockIdx.x >> 1;
  int half = blockIdx.x & 1;
  if (w >= meta[1]) return;          // block-uniform
  int u = cusers[w];

  __shared__ int   s_items[CMAX];
  __shared__ float s_cnts[CMAX];
  int Dpad = meta[0];
  for (int i = threadIdx.x; i < Dpad; i += 256) {
    s_items[i] = citems[i];
    s_cnts[i]  = ccnts[i];
  }
  __syncthreads();

  int Dh = Dpad >> 1;                 // multiple of 8
  const float4* Tu4 = (const float4*)(T + ((size_t)u << 20));  // u*1024*1024
  int tid = threadIdx.x;              // float4 column in [0,256)
  float4 acc = make_float4(0.0f, 0.0f, 0.0f, 0.0f);

  int d0 = half * Dh;
  for (int d = d0; d < d0 + Dh; d += 8) {
    int   idx[8];
    float cf[8];
#pragma unroll
    for (int k = 0; k < 8; ++k) { idx[k] = s_items[d + k]; cf[k] = s_cnts[d + k]; }
    float4 t[8];
#pragma unroll
    for (int k = 0; k < 8; ++k) t[k] = Tu4[(size_t)idx[k] * 256 + tid];
#pragma unroll
    for (int k = 0; k < 8; ++k) {
      acc.x = fmaf(cf[k], t[k].x, acc.x);
      acc.y = fmaf(cf[k], t[k].y, acc.y);
      acc.z = fmaf(cf[k], t[k].z, acc.z);
      acc.w = fmaf(cf[k], t[k].w, acc.w);
    }
  }
  float4* dst = (float4*)(rs2 + ((size_t)(half * U_CNT + u) << 10));
  dst[tid] = acc;
}

// ---------------- Kernel C: v_u = normalize(sel @ gi); emit all outputs -----
// grid = U blocks (compacted users), 256 threads. After computing v/||v||,
// each wave scans its quarter of the batch and writes xui/gamma_u/gamma_i_i
// for every b with users[b]==u (fuses old out_kernel).
__global__ __launch_bounds__(256) void gamma_out_kernel(
    const float* __restrict__ rs2, const float* __restrict__ gi,
    const int* __restrict__ items, const int* __restrict__ users,
    const int* __restrict__ cusers, const int* __restrict__ meta,
    const float* __restrict__ gu, float* __restrict__ out) {
  int w = blockIdx.x;
  if (w >= meta[1]) return;
  int u = cusers[w];

  __shared__ float wgt[B_CNT];
  __shared__ int   s_users[B_CNT];
  __shared__ float partial[4][E_CNT];
  __shared__ float vsh[E_CNT];
  int tid = threadIdx.x;
  const float* rsA = rs2 + ((size_t)u << 10);
  const float* rsB = rs2 + ((size_t)(U_CNT + u) << 10);
  for (int j = tid; j < B_CNT; j += 256) {
    int it = items[j];
    wgt[j]     = rsA[it] + rsB[it];
    s_users[j] = users[j];
  }
  __syncthreads();

  int e = tid & 63, q = tid >> 6;
  float acc = 0.0f;
  int j0 = q * 128;
#pragma unroll 4
  for (int j = j0; j < j0 + 128; ++j) acc = fmaf(wgt[j], gi[j * E_CNT + e], acc);
  partial[q][e] = acc;
  __syncthreads();

  if (q == 0) {  // wave 0 finishes the reduction + normalization
    float v = partial[0][e] + partial[1][e] + partial[2][e] + partial[3][e];
    float sq = v * v;
    for (int off = 32; off > 0; off >>= 1) sq += __shfl_down(sq, off);
    float n = __shfl(sq, 0);
    n = fmaxf(sqrtf(n), 1e-12f);
    vsh[e] = v / n;
  }
  __syncthreads();

  float vi = vsh[e];
  int b0 = q * 128;
  for (int b = b0; b < b0 + 128; ++b) {
    if (s_users[b] == u) {           // wave-uniform branch (s_users[b] scalar)
      float g = gu[b * E_CNT + e];
      out[B_CNT + b * E_CNT + e] = g;                    // gamma_u
      out[B_CNT + B_CNT * E_CNT + b * E_CNT + e] = vi;   // gamma_i_i
      float p = g * vi;
      for (int off = 32; off > 0; off >>= 1) p += __shfl_down(p, off);
      if (e == 0) out[b] = p;                            // xui
    }
  }
}

extern "C" void kernel_launch(void* const* d_in, const int* in_sizes, int n_in,
                              void* d_out, int out_size, void* d_ws, size_t ws_size,
                              hipStream_t stream) {
  const float* T     = (const float*)d_in[0];
  const float* gu    = (const float*)d_in[1];
  const float* gi    = (const float*)d_in[2];
  const int*   users = (const int*)d_in[3];
  const int*   items = (const int*)d_in[4];
  float* out = (float*)d_out;

  // Workspace layout
  float* rs2    = (float*)d_ws;                   // 2 * 256 * 1024 floats (2 MB)
  int*   citems = (int*)(rs2 + 2 * U_CNT * I_CNT); // CMAX
  float* ccnts  = (float*)(citems + CMAX);         // CMAX
  int*   cusers = (int*)(ccnts + CMAX);            // U_CNT
  int*   meta   = cusers + U_CNT;                  // 8

  hipLaunchKernelGGL(setup_kernel, dim3(1), dim3(1024), 0, stream,
                     users, items, citems, ccnts, cusers, meta);
  hipLaunchKernelGGL(rowsum_kernel, dim3(2 * U_CNT), dim3(256), 0, stream,
                     T, citems, ccnts, cusers, meta, rs2);
  hipLaunchKernelGGL(gamma_out_kernel, dim3(U_CNT), dim3(256), 0, stream,
                     rs2, gi, items, users, cusers, meta, gu, out);
}